// Round 15
// baseline (149.884 us; speedup 1.0000x reference)
//
#include <hip/hip_runtime.h>
#include <math.h>

#define TOKENS 16384
#define DIM 2048
#define NE 8
#define BLOCK 1024             // 16 waves: 0-7 gate, 8-15 noise (same 64 tokens)
#define GRID 256               // 256 blocks x 64 tokens
#define NCHUNK (DIM / 256)     // 8 chunks of 64 float4

// launch_bounds only sets MIN waves/EU -> allocator still targeted 8/EU (64 regs)
// and spilled (R4/R12/R13). amdgpu_waves_per_eu(4,4) pins target occupancy to
// exactly 4 waves/EU: reg budget 128, no incentive to shrink to 64.
__global__ void
__launch_bounds__(BLOCK)
__attribute__((amdgpu_waves_per_eu(4, 4)))
router_kernel(const float* __restrict__ x,
              const float* __restrict__ w_g,
              const float* __restrict__ w_noise,
              const float* __restrict__ eps,
              float* __restrict__ out)
{
    __shared__ float wlds[16 * DIM];   // 128 KiB: rows 0..7 = w_g, 8..15 = w_noise
    __shared__ float nbuf[8][64];      // 2 KiB: noise handoff [token-octet][t*8+e]

    const int tid  = threadIdx.x;
    const int lane = tid & 63;
    const int wv   = tid >> 6;         // 0..15
    const int role = wv >> 3;          // 0: gate rows, 1: noise rows
    const int grpw = wv & 7;           // token-octet within block
    const int t0   = blockIdx.x * 64 + grpw * 8;

    const float4* x4 = (const float4*)x;

    // ---- preload chunk-0 x (latency overlaps weight staging) ----
    float4 xv[8];
    #pragma unroll
    for (int t = 0; t < 8; ++t)
        xv[t] = x4[(t0 + t) * (DIM / 4) + lane];

    // noise waves: coalesced eps — lane L gets eps for (t=L>>3, e=L&7)
    float ev = 0.f;
    if (role) ev = eps[t0 * NE + lane];

    // ---- stage weights (coalesced float4) ----
    {
        const float4* g4 = (const float4*)w_g;
        const float4* n4 = (const float4*)w_noise;
        float4* l4 = (float4*)wlds;
        #pragma unroll
        for (int i = tid; i < (NE * DIM) / 4; i += BLOCK) {
            l4[i] = g4[i];
            l4[i + (NE * DIM) / 4] = n4[i];
        }
    }
    __syncthreads();

    const float4* wl4 = (const float4*)wlds + role * (NE * DIM / 4);

    // V[t*8+r]: partial dot of row (role*8+r) with token t0+t over lane's slice
    float V[64];
    #pragma unroll
    for (int v = 0; v < 64; ++v) V[v] = 0.f;

    #pragma unroll 1                   // rolled: bound live ranges across back-edge
    for (int k = 0; k < NCHUNK; ++k) {
        #pragma unroll
        for (int r = 0; r < 8; ++r) {
            const float4 w = wl4[r * (DIM / 4) + k * 64 + lane];
            #pragma unroll
            for (int t = 0; t < 8; ++t) {
                float a = V[t * 8 + r];
                a = fmaf(xv[t].x, w.x, a);
                a = fmaf(xv[t].y, w.y, a);
                a = fmaf(xv[t].z, w.z, a);
                a = fmaf(xv[t].w, w.w, a);
                V[t * 8 + r] = a;
            }
        }
        if (k < NCHUNK - 1) {          // use-then-refill (WAR): same regs, no 2nd buffer
            #pragma unroll
            for (int t = 0; t < 8; ++t)
                xv[t] = x4[(t0 + t) * (DIM / 4) + (k + 1) * 64 + lane];
        }
    }

    // ---- pack-halving reduction (validated): lane L ends with sum of V[L] ----
    #pragma unroll
    for (int s = 0; s < 6; ++s) {
        const int m = 1 << s;
        const int n = 64 >> s;
        #pragma unroll
        for (int j = 0; j < n / 2; ++j) {
            const float A = V[2 * j];
            const float B = V[2 * j + 1];
            const float As = __shfl_xor(A, m, 64);
            const float Bs = __shfl_xor(B, m, 64);
            V[j] = (lane & m) ? (B + Bs) : (A + As);
        }
    }
    const float mine = V[0];           // lane L: token t0+(L>>3), expert (L&7)

    if (role) {
        // stable softplus, scale by eps, hand to gate wave via LDS
        const float sp = fmaxf(mine, 0.f) + log1pf(expf(-fabsf(mine)));
        nbuf[grpw][lane] = sp * ev;
    }
    __syncthreads();
    if (!role) {
        const float logit = mine + nbuf[grpw][lane];
        const int e = lane & 7;
        const int t = lane >> 3;

        // top-2 across the 8 lanes sharing token t (e = lane bits 0..2)
        float v1 = logit, v2 = -INFINITY;
        int   i1 = e,     i2 = 7;
        #pragma unroll
        for (int sm = 0; sm <= 2; ++sm) {
            const int m = 1 << sm;
            const float ov1 = __shfl_xor(v1, m, 64);
            const float ov2 = __shfl_xor(v2, m, 64);
            const int   oi1 = __shfl_xor(i1, m, 64);
            const int   oi2 = __shfl_xor(i2, m, 64);
            // merge two (desc-value, asc-index) sorted pairs
            const bool firstA = (v1 > ov1) || (v1 == ov1 && i1 < oi1);
            const float nv1 = firstA ? v1  : ov1;
            const int   ni1 = firstA ? i1  : oi1;
            const float ca  = firstA ? ov1 : v1;    // losing head
            const int   cia = firstA ? oi1 : i1;
            const float cb  = firstA ? v2  : ov2;   // winner's second
            const int   cib = firstA ? i2  : oi2;
            const bool secondA = (ca > cb) || (ca == cb && cia < cib);
            v1 = nv1; i1 = ni1;
            v2 = secondA ? ca : cb;
            i2 = secondA ? cia : cib;
        }

        if (e == 0) {                  // 8 writer lanes: L = t*8
            const int tok = t0 + t;
            *(float2*)&out[2 * tok] = make_float2(v1, v2);
            *(float2*)&out[2 * TOKENS + 2 * tok] = make_float2((float)i1, (float)i2);
        }
    }
}

extern "C" void kernel_launch(void* const* d_in, const int* in_sizes, int n_in,
                              void* d_out, int out_size, void* d_ws, size_t ws_size,
                              hipStream_t stream) {
    const float* x       = (const float*)d_in[0];
    const float* w_g     = (const float*)d_in[1];
    const float* w_noise = (const float*)d_in[2];
    const float* eps     = (const float*)d_in[3];
    float* out = (float*)d_out;

    router_kernel<<<GRID, BLOCK, 0, stream>>>(x, w_g, w_noise, eps, out);
}

// Round 16
// 35.999 us; speedup vs baseline: 4.1635x; 4.1635x over previous
//
#include <hip/hip_runtime.h>
#include <math.h>

#define TOKENS 16384
#define DIM 2048
#define NE 8
#define BLOCK 1024             // 16 waves: 0-7 gate, 8-15 noise (same 64 tokens)
#define GRID 256               // 256 blocks x 64 tokens
#define NCHUNK (DIM / 256)     // 8 chunks of 64 float4

// ALLOCATION REGIME NOTE (R4/R10-R15 forensics): with a ROLLED k-loop the
// allocator targets 8 waves/EU (64 VGPR) and deliberately spills V[64] ->
// 360 MB scratch traffic, regardless of launch_bounds / waves_per_eu hints.
// The FULLY-UNROLLED loop shape (R10/R11) reliably allocates >=128. So:
// full unroll + (1024,4), matching R10/R11 exactly.
__launch_bounds__(BLOCK, 4)
__global__ void router_kernel(const float* __restrict__ x,
                              const float* __restrict__ w_g,
                              const float* __restrict__ w_noise,
                              const float* __restrict__ eps,
                              float* __restrict__ out)
{
    __shared__ float wlds[16 * DIM];   // 128 KiB: rows 0..7 = w_g, 8..15 = w_noise
    __shared__ float nbuf[8][64];      // 2 KiB: noise handoff [token-octet][t*8+e]

    const int tid  = threadIdx.x;
    const int lane = tid & 63;
    const int wv   = tid >> 6;         // 0..15
    const int role = wv >> 3;          // 0: gate rows, 1: noise rows
    const int grpw = wv & 7;           // token-octet within block
    const int t0   = blockIdx.x * 64 + grpw * 8;

    // convoy-breaker (R11, +1.5us): per-wave chunk phase. Partner waves wv and
    // wv+8 have equal (wv&3) -> identical order -> shared-x L2 locality kept.
    const int off  = (wv & 3) * 2;

    const float4* x4 = (const float4*)x;

    // ---- preload first chunk's x (latency overlaps weight staging) ----
    float4 xv[8];
    #pragma unroll
    for (int t = 0; t < 8; ++t)
        xv[t] = x4[(t0 + t) * (DIM / 4) + off * 64 + lane];

    // noise waves: coalesced eps — lane L gets eps for (t=L>>3, e=L&7)
    float ev = 0.f;
    if (role) ev = eps[t0 * NE + lane];

    // ---- stage weights (coalesced float4) ----
    {
        const float4* g4 = (const float4*)w_g;
        const float4* n4 = (const float4*)w_noise;
        float4* l4 = (float4*)wlds;
        #pragma unroll
        for (int i = tid; i < (NE * DIM) / 4; i += BLOCK) {
            l4[i] = g4[i];
            l4[i + (NE * DIM) / 4] = n4[i];
        }
    }
    __syncthreads();

    const float4* wl4 = (const float4*)wlds + role * (NE * DIM / 4);

    // V[t*8+r]: partial dot of row (role*8+r) with token t0+t over lane's slice
    float V[64];
    #pragma unroll
    for (int v = 0; v < 64; ++v) V[v] = 0.f;

    #pragma unroll                     // FULL unroll — the proven-no-spill shape
    for (int i = 0; i < NCHUNK; ++i) {
        const int k = (i + off) & 7;
        #pragma unroll
        for (int r = 0; r < 8; ++r) {
            const float4 w = wl4[r * (DIM / 4) + k * 64 + lane];
            #pragma unroll
            for (int t = 0; t < 8; ++t) {
                float a = V[t * 8 + r];
                a = fmaf(xv[t].x, w.x, a);
                a = fmaf(xv[t].y, w.y, a);
                a = fmaf(xv[t].z, w.z, a);
                a = fmaf(xv[t].w, w.w, a);
                V[t * 8 + r] = a;
            }
        }
        if (i + 1 < NCHUNK) {          // use-then-refill (WAR), single buffer
            const int kn = (i + 1 + off) & 7;
            #pragma unroll
            for (int t = 0; t < 8; ++t)
                xv[t] = x4[(t0 + t) * (DIM / 4) + kn * 64 + lane];
        }
    }

    // ---- pack-halving reduction (validated): lane L ends with sum of V[L] ----
    #pragma unroll
    for (int s = 0; s < 6; ++s) {
        const int m = 1 << s;
        const int n = 64 >> s;
        #pragma unroll
        for (int j = 0; j < n / 2; ++j) {
            const float A = V[2 * j];
            const float B = V[2 * j + 1];
            const float As = __shfl_xor(A, m, 64);
            const float Bs = __shfl_xor(B, m, 64);
            V[j] = (lane & m) ? (B + Bs) : (A + As);
        }
    }
    const float mine = V[0];           // lane L: token t0+(L>>3), expert (L&7)

    if (role) {
        // stable softplus, scale by eps, hand to gate wave via LDS
        const float sp = fmaxf(mine, 0.f) + log1pf(expf(-fabsf(mine)));
        nbuf[grpw][lane] = sp * ev;
    }
    __syncthreads();
    if (!role) {
        const float logit = mine + nbuf[grpw][lane];
        const int e = lane & 7;
        const int t = lane >> 3;

        // top-2 across the 8 lanes sharing token t (e = lane bits 0..2)
        float v1 = logit, v2 = -INFINITY;
        int   i1 = e,     i2 = 7;
        #pragma unroll
        for (int sm = 0; sm <= 2; ++sm) {
            const int m = 1 << sm;
            const float ov1 = __shfl_xor(v1, m, 64);
            const float ov2 = __shfl_xor(v2, m, 64);
            const int   oi1 = __shfl_xor(i1, m, 64);
            const int   oi2 = __shfl_xor(i2, m, 64);
            // merge two (desc-value, asc-index) sorted pairs
            const bool firstA = (v1 > ov1) || (v1 == ov1 && i1 < oi1);
            const float nv1 = firstA ? v1  : ov1;
            const int   ni1 = firstA ? i1  : oi1;
            const float ca  = firstA ? ov1 : v1;    // losing head
            const int   cia = firstA ? oi1 : i1;
            const float cb  = firstA ? v2  : ov2;   // winner's second
            const int   cib = firstA ? i2  : oi2;
            const bool secondA = (ca > cb) || (ca == cb && cia < cib);
            v1 = nv1; i1 = ni1;
            v2 = secondA ? ca : cb;
            i2 = secondA ? cia : cib;
        }

        if (e == 0) {                  // 8 writer lanes: L = t*8
            const int tok = t0 + t;
            *(float2*)&out[2 * tok] = make_float2(v1, v2);
            *(float2*)&out[2 * TOKENS + 2 * tok] = make_float2((float)i1, (float)i2);
        }
    }
}

extern "C" void kernel_launch(void* const* d_in, const int* in_sizes, int n_in,
                              void* d_out, int out_size, void* d_ws, size_t ws_size,
                              hipStream_t stream) {
    const float* x       = (const float*)d_in[0];
    const float* w_g     = (const float*)d_in[1];
    const float* w_noise = (const float*)d_in[2];
    const float* eps     = (const float*)d_in[3];
    float* out = (float*)d_out;

    router_kernel<<<GRID, BLOCK, 0, stream>>>(x, w_g, w_noise, eps, out);
}

// Round 17
// 31.796 us; speedup vs baseline: 4.7139x; 1.1322x over previous
//
#include <hip/hip_runtime.h>
#include <math.h>

#define TOKENS 16384
#define DIM 2048
#define NE 8
#define BLOCK 1024             // 16 waves, 1 block/CU (128 KiB LDS)
#define GRID 256
#define NCHUNK (DIM / 256)     // 8 chunks of 64 float4

// DPP cross-lane (VALU pipe, not DS): quad_perm patterns give xor-1 / xor-2.
template <int CTRL>
__device__ __forceinline__ float dpp_xor(float v) {
    return __int_as_float(__builtin_amdgcn_update_dpp(
        0, __float_as_int(v), CTRL, 0xf, 0xf, true));
}
#define DPP_XOR1 0xB1   // quad_perm [1,0,3,2]
#define DPP_XOR2 0x4E   // quad_perm [2,3,0,1]

__launch_bounds__(BLOCK, 4)   // full-unroll shape: allocator picks >=128 VGPR (R10/R11/R16)
__global__ void router_kernel(const float* __restrict__ x,
                              const float* __restrict__ w_g,
                              const float* __restrict__ w_noise,
                              const float* __restrict__ eps,
                              float* __restrict__ out)
{
    __shared__ float wlds[16 * DIM];   // rows 0..7 = w_g, 8..15 = w_noise

    const int tid  = threadIdx.x;
    const int lane = tid & 63;
    const int wv   = tid >> 6;                   // 0..15
    const int t0   = (blockIdx.x * 16 + wv) * 4; // this wave's 4 tokens

    // convoy-breaker (R11, validated): per-wave chunk phase
    const int off  = (wv & 3) * 2;

    const float4* x4 = (const float4*)x;

    // ---- issue x loads for steps 0/1 FIRST: latency overlaps weight staging ----
    float4 xvA[4], xvB[4];
    {
        const int c0 = off;
        const int c1 = (1 + off) & 7;
        #pragma unroll
        for (int t = 0; t < 4; ++t) xvA[t] = x4[(t0 + t) * (DIM / 4) + c0 * 64 + lane];
        #pragma unroll
        for (int t = 0; t < 4; ++t) xvB[t] = x4[(t0 + t) * (DIM / 4) + c1 * 64 + lane];
    }

    // early eps (lanes<32): eps[t0*8 .. t0*8+31] for this wave's 4 tokens
    float my_eps = 0.f;
    if (lane < 32) my_eps = eps[t0 * NE + lane];

    // ---- stage weights (coalesced float4) ----
    {
        const float4* g4 = (const float4*)w_g;
        const float4* n4 = (const float4*)w_noise;
        float4* l4 = (float4*)wlds;
        #pragma unroll
        for (int i = tid; i < (NE * DIM) / 4; i += BLOCK) {
            l4[i] = g4[i];
            l4[i + (NE * DIM) / 4] = n4[i];
        }
    }
    __syncthreads();

    const float4* wl4 = (const float4*)wlds;

    // V[r*4+t]: partial dot of row r (0..15) with token t0+t
    float V[64];
    #pragma unroll
    for (int v = 0; v < 64; ++v) V[v] = 0.f;

    // ---- k-loop, chunk = (i+off)&7, unrolled x2, 2-buffer refill (R11) ----
    #pragma unroll
    for (int i = 0; i < NCHUNK; i += 2) {
        const int kA = (i + off) & 7;
        const int kB = (i + 1 + off) & 7;

        #pragma unroll
        for (int r = 0; r < 16; ++r) {
            const float4 w = wl4[r * (DIM / 4) + kA * 64 + lane];
            #pragma unroll
            for (int t = 0; t < 4; ++t) {
                float a = V[r * 4 + t];
                a = fmaf(xvA[t].x, w.x, a);
                a = fmaf(xvA[t].y, w.y, a);
                a = fmaf(xvA[t].z, w.z, a);
                a = fmaf(xvA[t].w, w.w, a);
                V[r * 4 + t] = a;
            }
        }
        if (i + 2 < NCHUNK) {
            const int kN = (i + 2 + off) & 7;
            #pragma unroll
            for (int t = 0; t < 4; ++t)
                xvA[t] = x4[(t0 + t) * (DIM / 4) + kN * 64 + lane];
        }
        #pragma unroll
        for (int r = 0; r < 16; ++r) {
            const float4 w = wl4[r * (DIM / 4) + kB * 64 + lane];
            #pragma unroll
            for (int t = 0; t < 4; ++t) {
                float a = V[r * 4 + t];
                a = fmaf(xvB[t].x, w.x, a);
                a = fmaf(xvB[t].y, w.y, a);
                a = fmaf(xvB[t].z, w.z, a);
                a = fmaf(xvB[t].w, w.w, a);
                V[r * 4 + t] = a;
            }
        }
        if (i + 3 < NCHUNK) {
            const int kN = (i + 3 + off) & 7;
            #pragma unroll
            for (int t = 0; t < 4; ++t)
                xvB[t] = x4[(t0 + t) * (DIM / 4) + kN * 64 + lane];
        }
    }

    // ---- pack-halving reduction: stages 0/1 on DPP (VALU pipe), 2..5 on shfl ----
    // Same values, same order as R11 -> bit-identical result; 126 -> 30 DS ops.
    #pragma unroll
    for (int j = 0; j < 32; ++j) {     // stage 0: xor-1 via quad_perm
        const float A = V[2 * j];
        const float B = V[2 * j + 1];
        const float As = dpp_xor<DPP_XOR1>(A);
        const float Bs = dpp_xor<DPP_XOR1>(B);
        V[j] = (lane & 1) ? (B + Bs) : (A + As);
    }
    #pragma unroll
    for (int j = 0; j < 16; ++j) {     // stage 1: xor-2 via quad_perm
        const float A = V[2 * j];
        const float B = V[2 * j + 1];
        const float As = dpp_xor<DPP_XOR2>(A);
        const float Bs = dpp_xor<DPP_XOR2>(B);
        V[j] = (lane & 2) ? (B + Bs) : (A + As);
    }
    #pragma unroll
    for (int s = 2; s < 6; ++s) {      // stages 2..5: xor 4/8/16/32 via shfl
        const int m = 1 << s;
        const int n = 64 >> s;
        #pragma unroll
        for (int j = 0; j < n / 2; ++j) {
            const float A = V[2 * j];
            const float B = V[2 * j + 1];
            const float As = __shfl_xor(A, m, 64);
            const float Bs = __shfl_xor(B, m, 64);
            V[j] = (lane & m) ? (B + Bs) : (A + As);
        }
    }
    const float mine = V[0];            // lane L: row (L>>2), token t0+(L&3)

    // lanes <32 hold gate sums (rows 0..7); lane+32 holds matching noise sum
    const float other = __shfl_xor(mine, 32, 64);

    if (lane < 32) {
        const int e = lane >> 2;
        const int t = lane & 3;
        const int tok = t0 + t;

        // eps[t*8+e] is held by lane (t<<3)|e
        const float ev = __shfl(my_eps, (t << 3) | e, 64);

        const float nv = other;
        const float sp = fmaxf(nv, 0.f) + log1pf(expf(-fabsf(nv)));  // stable softplus
        const float logit = fmaf(sp, ev, mine);

        // top-2 across the 8 lanes sharing token t (e lives in lane bits 2..4)
        float v1 = logit, v2 = -INFINITY;
        int   i1 = e,     i2 = 7;
        #pragma unroll
        for (int sm = 2; sm <= 4; ++sm) {
            const int m = 1 << sm;
            const float ov1 = __shfl_xor(v1, m, 64);
            const float ov2 = __shfl_xor(v2, m, 64);
            const int   oi1 = __shfl_xor(i1, m, 64);
            const int   oi2 = __shfl_xor(i2, m, 64);
            // merge two (desc-value, asc-index) sorted pairs
            const bool firstA = (v1 > ov1) || (v1 == ov1 && i1 < oi1);
            const float nv1 = firstA ? v1  : ov1;
            const int   ni1 = firstA ? i1  : oi1;
            const float ca  = firstA ? ov1 : v1;    // losing head
            const int   cia = firstA ? oi1 : i1;
            const float cb  = firstA ? v2  : ov2;   // winner's second
            const int   cib = firstA ? i2  : oi2;
            const bool secondA = (ca > cb) || (ca == cb && cia < cib);
            v1 = nv1; i1 = ni1;
            v2 = secondA ? ca : cb;
            i2 = secondA ? cia : cib;
        }

        if (e == 0) {                   // lanes 0..3: lane == t
            *(float2*)&out[2 * tok] = make_float2(v1, v2);
            *(float2*)&out[2 * TOKENS + 2 * tok] = make_float2((float)i1, (float)i2);
        }
    }
}

extern "C" void kernel_launch(void* const* d_in, const int* in_sizes, int n_in,
                              void* d_out, int out_size, void* d_ws, size_t ws_size,
                              hipStream_t stream) {
    const float* x       = (const float*)d_in[0];
    const float* w_g     = (const float*)d_in[1];
    const float* w_noise = (const float*)d_in[2];
    const float* eps     = (const float*)d_in[3];
    float* out = (float*)d_out;

    router_kernel<<<GRID, BLOCK, 0, stream>>>(x, w_g, w_noise, eps, out);
}